// Round 11
// baseline (190.464 us; speedup 1.0000x reference)
//
#include <hip/hip_runtime.h>
#include <hip/hip_bf16.h>

// EfficientAttention: x(4,256,64,64) -> qkv(192ch) -> attn(N=4096,c=64) -> proj(256ch)
// R11: FULL FUSION into one kernel + grid barrier.
//   Accounting across R0-R10: non-attn time is 72-77us under SEVEN different
//   qkv structures, and no kernel but k_attn (~56us) ever enters the top-5 ->
//   k_qkv ~45-55us structure-invariant + k_prep + 2 launch gaps. Both big
//   kernels pin at ~55us whatever they do => test whether the cost is
//   per-dispatch by collapsing to ONE dispatch.
//   Safety: 158KB LDS -> 1 block/CU; grid 256 = CU count -> all blocks
//   co-resident -> counter-spin barrier cannot deadlock. ctr zeroed per
//   launch by a 4B hipMemsetAsync (graph-capturable). Release = threadfence
//   (device scope, L2 wb to coherent LLC); acquire = AGENT-scope atomic load
//   (L1 inv). First-iteration absmax would catch visibility bugs.
// Phase 1 (per block = (b, 64-token tile)): R0's verified 6-wave qkv body;
//   weights converted fp32->bf16 inline (qw L2-resident; kills k_prep);
//   Q frags -> LDS ONLY (block-local, never crosses blocks); K/V frags -> ws.
// Phase 2: R6 k_attn verbatim (best measured 56us), Q read from LDS.
//   Kf/Vf: [b][chunk32][kk(4)][lane(64)][8] / [b][chunk32][ct2 ks2][lane][8]

#define N_TOK 4096
#define CDIM  64
#define DIM   256
#define NBAT  4

typedef __attribute__((ext_vector_type(8)))  short          short8;
typedef __attribute__((ext_vector_type(8)))  unsigned short ushort8_t;
typedef __attribute__((ext_vector_type(4)))  unsigned short ushort4_t;
typedef __attribute__((ext_vector_type(4)))  unsigned int   uint4_t;
typedef __attribute__((ext_vector_type(4)))  float          float4_t;
typedef __attribute__((ext_vector_type(16))) float          float16_t;

#if __has_builtin(__builtin_amdgcn_exp2f)
#define QSC  0.18033688011112042f   /* 0.125 * log2(e): p = exp2(s) */
#define PEXP(x) __builtin_amdgcn_exp2f(x)
#else
#define QSC  0.125f
#define PEXP(x) __expf(x)
#endif

__device__ __forceinline__ unsigned short f2bf(float f) {
  unsigned int u = __builtin_bit_cast(unsigned int, f);
  u += 0x7fffu + ((u >> 16) & 1u);            // RNE
  return (unsigned short)(u >> 16);
}

// packed f32x2 -> bf16x2 dword (v_cvt_pk_bf16_f32 on gfx950, RNE)
__device__ __forceinline__ unsigned int pkcv(float a, float b) {
  __hip_bfloat162 h = __float22bfloat162_rn(make_float2(a, b));
  unsigned int r; __builtin_memcpy(&r, &h, 4); return r;
}

__device__ __forceinline__ short8 ld8(const unsigned short* p) {
  return __builtin_bit_cast(short8, *(const ushort8_t*)p);
}

__device__ __forceinline__ short8 pack8f(float4_t a, float4_t b) {
  uint4_t u;
  u[0] = pkcv(a[0], a[1]); u[1] = pkcv(a[2], a[3]);
  u[2] = pkcv(b[0], b[1]); u[3] = pkcv(b[2], b[3]);
  return __builtin_bit_cast(short8, u);
}

__device__ __forceinline__ float16_t z16() {
  float16_t r;
#pragma unroll
  for (int i = 0; i < 16; ++i) r[i] = 0.0f;
  return r;
}

// async global->LDS DMA: 64 lanes x 16B; LDS dst = wave-uniform base (+lane*16 by HW)
typedef __attribute__((address_space(1))) const void* gvp;
typedef __attribute__((address_space(3))) void*       lvp;
__device__ __forceinline__ void dma16(const unsigned short* g, unsigned short* l) {
  __builtin_amdgcn_global_load_lds((gvp)g, (lvp)l, 16, 0, 0);
}

#define MFMA(a, b, c) __builtin_amdgcn_mfma_f32_32x32x16_bf16((a), (b), (c), 0, 0, 0)

// ws layout (u16 units)
#define KOFF  1048576
#define VOFF  2097152
#define CTOFF 3145728          // barrier counter (u32), zeroed per launch

#define RS   132   // Xl row stride in dwords
#define OS   68    // Oacc row stride (fp32)
#define OLS  72    // Ol row stride (bf16)
#define NACC (64 * OS + 64)

// device-scope grid barrier: all 256 blocks co-resident (1 block/CU, grid=CU#)
__device__ __forceinline__ void grid_barrier(unsigned int* ctr) {
  __threadfence();            // release: K/V frag stores -> device-coherent
  __syncthreads();            // all waves of this block past their stores
  if (threadIdx.x == 0) {
    __hip_atomic_fetch_add(ctr, 1u, __ATOMIC_ACQ_REL, __HIP_MEMORY_SCOPE_AGENT);
    unsigned int v;
    do {
      __builtin_amdgcn_s_sleep(2);
      v = __hip_atomic_load(ctr, __ATOMIC_ACQUIRE, __HIP_MEMORY_SCOPE_AGENT);
    } while (v < 256u);
  }
  __syncthreads();            // block-wide release after acquire
}

// ---------------------------------------------------------------------------
// k_fused: grid 256 x 512 thr (8 waves). Block = (b, nt 64-token q-tile).
// ---------------------------------------------------------------------------
__global__ __launch_bounds__(512, 1) void k_fused(
    const float* __restrict__ x, const float* __restrict__ qw,
    const float* __restrict__ qb, const float* __restrict__ pw,
    const float* __restrict__ pb, unsigned short* __restrict__ Kf,
    unsigned short* __restrict__ Vf, float* __restrict__ out,
    unsigned int* __restrict__ ctr)
{
  __shared__ __align__(16) unsigned short Kl[2][32768];   // 128KB (ph2); Xl alias (ph1)
  __shared__ float Oacc[NACC];                            // O[n][c] + den tail
  __shared__ __align__(16) unsigned short Ol[64 * OLS];   // ph1: Ql alias (8KB)

  const int id = blockIdx.x;
  const int b  = (id >> 1) & 3;
  const int nt = (id & 1) | ((id >> 3) << 1);        // 0..63
  const int t  = threadIdx.x;
  const int wv = t >> 6, lane = t & 63, l31 = lane & 31, lh = lane >> 5;

  unsigned short* Ql = &Ol[0];

  // ======================= phase 1: qkv (R0 6-wave body) ====================
  {
    unsigned int* Xl = (unsigned int*)&Kl[0][0];     // 64 x RS dwords = 33KB
    const int n0g = nt * 64;

    // stage x tile (64 tokens x 256 c) as bf16x2-packed dwords, all 512 thr
    {
      const int n0  = (t & 15) * 4;
      const int cpb = t >> 4;                        // 0..31
#pragma unroll
      for (int p = 0; p < 4; ++p) {
        const int cp = cpb + 32 * p, c = cp * 2;
        const float* xb = x + (((size_t)(b * DIM + c)) << 12) + n0g + n0;
        float4_t a = *(const float4_t*)xb;
        float4_t d = *(const float4_t*)(xb + 4096);
#pragma unroll
        for (int j = 0; j < 4; ++j)
          Xl[(n0 + j) * RS + cp] = pkcv(a[j], d[j]);
      }
    }

    // inline weight frags (fp32 -> bf16, QSC folded into Q rows); waves 0-5
    short8 wf[16];
    if (wv < 6) {
      const float sc = (wv < 2) ? QSC : 1.0f;
      const float* qwr = qw + (wv * 32 + l31) * 256 + lh * 8;
#pragma unroll
      for (int kk = 0; kk < 16; ++kk) {
        const float* s = qwr + kk * 16;
        ushort8_t u;
#pragma unroll
        for (int j = 0; j < 8; ++j) u[j] = f2bf(s[j] * sc);
        wf[kk] = __builtin_bit_cast(short8, u);
      }
    }
    __syncthreads();   // Xl resident

    if (wv < 6) {
      const unsigned int* xr0 = &Xl[l31 * RS + lh * 4];
      const unsigned int* xr1 = &Xl[(32 + l31) * RS + lh * 4];
      float16_t a0 = z16(), a1 = z16();
      if (wv < 4) {
#pragma unroll
        for (int kk = 0; kk < 16; ++kk) {
          short8 x0 = __builtin_bit_cast(short8, *(const uint4_t*)(xr0 + kk * 8));
          short8 x1 = __builtin_bit_cast(short8, *(const uint4_t*)(xr1 + kk * 8));
          a0 = MFMA(wf[kk], x0, a0);               // C[o rows][n cols]
          a1 = MFMA(wf[kk], x1, a1);
        }
      } else {
#pragma unroll
        for (int kk = 0; kk < 16; ++kk) {
          short8 x0 = __builtin_bit_cast(short8, *(const uint4_t*)(xr0 + kk * 8));
          short8 x1 = __builtin_bit_cast(short8, *(const uint4_t*)(xr1 + kk * 8));
          a0 = MFMA(x0, wf[kk], a0);               // C[token rows][c cols]
          a1 = MFMA(x1, wf[kk], a1);
        }
      }

      if (wv < 2) {
        // Q -> LDS only (block-local; o = wv*32+.. < 64 -> bias scaled)
#pragma unroll
        for (int sub = 0; sub < 2; ++sub) {
          const float16_t& aa = sub ? a1 : a0;
#pragma unroll
          for (int p = 0; p < 4; ++p) {
            const int o = wv * 32 + p * 8 + lh * 4;
            float4_t bv = *(const float4_t*)(qb + o);
            ushort4_t pk4;
#pragma unroll
            for (int q = 0; q < 4; ++q)
              pk4[q] = f2bf(aa[p * 4 + q] + bv[q] * QSC);
            const int kkt = (wv & 1) * 2 + (p >> 1);
            *(ushort4_t*)(Ql + (((sub * 4 + kkt) << 9)
                           + (l31 + 32 * (p & 1)) * 8 + lh * 4)) = pk4;
          }
        }
      } else if (wv < 4) {
        // K -> global ws frags
        const int w2 = wv & 1;                     // c64-half
#pragma unroll
        for (int sub = 0; sub < 2; ++sub) {
          const float16_t& aa = sub ? a1 : a0;
          const int ch = nt * 2 + sub;
#pragma unroll
          for (int p = 0; p < 4; ++p) {
            const int o = wv * 32 + p * 8 + lh * 4;   // 64..127
            float4_t bv = *(const float4_t*)(qb + o);
            ushort4_t pk4;
#pragma unroll
            for (int q = 0; q < 4; ++q) pk4[q] = f2bf(aa[p * 4 + q] + bv[q]);
            const int kkt = w2 * 2 + (p >> 1);
            *(ushort4_t*)(Kf + ((((b * 128 + ch) * 4 + kkt) << 9)
                           + (l31 + 32 * (p & 1)) * 8 + lh * 4)) = pk4;
          }
        }
      } else {
        // V -> global ws frags (producer reg order)
        const int ct = wv - 4;
        const float bvs = qb[128 + ct * 32 + l31];
#pragma unroll
        for (int sub = 0; sub < 2; ++sub) {
          const float16_t& aa = sub ? a1 : a0;
          const int ch = nt * 2 + sub;
#pragma unroll
          for (int ks = 0; ks < 2; ++ks) {
            ushort8_t pk8;
#pragma unroll
            for (int j = 0; j < 8; ++j) pk8[j] = f2bf(aa[ks * 8 + j] + bvs);
            *(ushort8_t*)(Vf + ((((b * 128 + ch) * 4 + ct * 2 + ks) << 9)
                            + lane * 8)) = pk8;
          }
        }
      }
    }
  }

  // =================== grid barrier: all K/V frags published =================
  grid_barrier(ctr);

  // ======================= phase 2: attn (R6 body) ==========================
  const int mq = wv >> 1, nsub = wv & 1;

  for (int i = t; i < NACC; i += 512) Oacc[i] = 0.0f;

  // Q frags from LDS (written by waves 0-1 in phase 1)
  short8 qf[4];
#pragma unroll
  for (int kk = 0; kk < 4; ++kk)
    qf[kk] = ld8(Ql + ((nsub * 4 + kk) << 9) + lane * 8);

  // staging role: wave stages K chunks {2wv, 2wv+1} of each 16-chunk tile
  const int wq2 = wv * 2;
  const unsigned short* sg = Kf + (((size_t)(b * 128 + wq2)) << 11) + lane * 8;
  const unsigned short* vbase = Vf + (((size_t)(b * 128)) << 11) + lane * 8;

  // stage tile 0 into buf 0
#pragma unroll
  for (int c2 = 0; c2 < 2; ++c2)
#pragma unroll
    for (int kk = 0; kk < 4; ++kk)
      dma16(sg + (c2 << 11) + (kk << 9),
            &Kl[0][((wq2 + c2) << 11) + (kk << 9)]);

  float16_t oc0 = z16(), oc1 = z16();
  float den = 0.0f;

  __syncthreads();   // Oacc zeroed + tile 0 resident

  for (int t8 = 0; t8 < 8; ++t8) {
    const int cur = t8 & 1;

    if (t8 < 7) {
      const unsigned short* g = sg + (((size_t)(t8 + 1)) << 15);
#pragma unroll
      for (int c2 = 0; c2 < 2; ++c2)
#pragma unroll
        for (int kk = 0; kk < 4; ++kk)
          dma16(g + (c2 << 11) + (kk << 9),
                &Kl[cur ^ 1][((wq2 + c2) << 11) + (kk << 9)]);
    }

#pragma unroll
    for (int cc = 0; cc < 4; ++cc) {
      const int ch = mq * 4 + cc;                    // my m-chunk in tile
      const unsigned short* kl = &Kl[cur][ch << 11];

      short8 kf0 = ld8(kl + lane * 8);
      short8 kf1 = ld8(kl + 512 + lane * 8);
      short8 kf2 = ld8(kl + 1024 + lane * 8);
      short8 kf3 = ld8(kl + 1536 + lane * 8);

      // S^T tile: lane col n = l31, row m = (e&3)+8*(e>>2)+4*lh
      float16_t s = z16();
      s = MFMA(kf0, qf[0], s);
      s = MFMA(kf1, qf[1], s);
      s = MFMA(kf2, qf[2], s);
      s = MFMA(kf3, qf[3], s);

      float p[16];
#pragma unroll
      for (int e = 0; e < 16; ++e) p[e] = PEXP(s[e]);
      {
        float d0 = (p[0] + p[1]) + (p[2] + p[3]);
        float d1 = (p[4] + p[5]) + (p[6] + p[7]);
        float d2 = (p[8] + p[9]) + (p[10] + p[11]);
        float d3 = (p[12] + p[13]) + (p[14] + p[15]);
        den += (d0 + d1) + (d2 + d3);
      }

      uint4_t w0, w1;
#pragma unroll
      for (int j = 0; j < 4; ++j) {
        w0[j] = pkcv(p[2 * j], p[2 * j + 1]);
        w1[j] = pkcv(p[8 + 2 * j], p[9 + 2 * j]);
      }
      short8 pf0 = __builtin_bit_cast(short8, w0);   // m 0..15 of chunk
      short8 pf1 = __builtin_bit_cast(short8, w1);   // m 16..31

      // V direct from global (L2/L3-resident; exp/pack covers latency)
      const unsigned short* vl = vbase + (((size_t)(t8 * 16 + ch)) << 11);
      short8 vf0 = ld8(vl);
      short8 vf1 = ld8(vl + 512);
      short8 vf2 = ld8(vl + 1024);
      short8 vf3 = ld8(vl + 1536);

      oc0 = MFMA(pf0, vf0, oc0);
      oc0 = MFMA(pf1, vf1, oc0);
      oc1 = MFMA(pf0, vf2, oc1);
      oc1 = MFMA(pf1, vf3, oc1);
    }

    __syncthreads();   // drains next-tile DMA + frees cur buffer
  }

  den += __shfl_xor(den, 32);   // combine lane halves (m coverage)

  // combine m-chunk partials: O[n][c] (+ den) via LDS atomics
#pragma unroll
  for (int ct = 0; ct < 2; ++ct) {
    const float16_t& oa = ct ? oc1 : oc0;
    const int cc = ct * 32 + l31;
#pragma unroll
    for (int e = 0; e < 16; ++e) {
      const int nr = nsub * 32 + (e & 3) + 8 * (e >> 2) + 4 * lh;
      atomicAdd(&Oacc[nr * OS + cc], oa[e]);
    }
  }
  if (lane < 32) atomicAdd(&Oacc[64 * OS + nsub * 32 + l31], den);
  __syncthreads();

  // normalize + cast -> Ol[n][c] bf16 (8 thr/row; overwrites Ql, qf in regs)
  {
    const int nloc = t >> 3, c8 = (t & 7) * 8;
    float4_t s0 = *(float4_t*)&Oacc[nloc * OS + c8];
    float4_t s1 = *(float4_t*)&Oacc[nloc * OS + c8 + 4];
    const float r = 1.0f / Oacc[64 * OS + nloc];
    uint4_t o4;
    o4[0] = pkcv(s0[0] * r, s0[1] * r);
    o4[1] = pkcv(s0[2] * r, s0[3] * r);
    o4[2] = pkcv(s1[0] * r, s1[1] * r);
    o4[3] = pkcv(s1[2] * r, s1[3] * r);
    *(uint4_t*)&Ol[nloc * OLS + c8] = o4;
  }
  __syncthreads();

  // fused proj: wave wv -> o-tile wv (32 o), both n-subtiles; raw fp32 W
  float16_t f0 = z16(), f1 = z16();
  const float* pwrow = pw + (wv * 32 + l31) * 64 + lh * 8;
#pragma unroll
  for (int kk = 0; kk < 4; ++kk) {
    float4_t wa = *(const float4_t*)(pwrow + kk * 16);
    float4_t wb = *(const float4_t*)(pwrow + kk * 16 + 4);
    short8 af = pack8f(wa, wb);
    short8 b0 = ld8(&Ol[l31 * OLS + kk * 16 + lh * 8]);
    short8 b1 = ld8(&Ol[(32 + l31) * OLS + kk * 16 + lh * 8]);
    f0 = MFMA(af, b0, f0);
    f1 = MFMA(af, b1, f1);
  }
  const int n0 = nt * 64;
#pragma unroll
  for (int e = 0; e < 16; ++e) {
    const int o = wv * 32 + (e & 3) + 8 * (e >> 2) + 4 * lh;
    const float bv = pb[o];
    out[((b * 256 + o) << 12) + n0 + l31]      = f0[e] + bv;
    out[((b * 256 + o) << 12) + n0 + 32 + l31] = f1[e] + bv;
  }
}

extern "C" void kernel_launch(void* const* d_in, const int* in_sizes, int n_in,
                              void* d_out, int out_size, void* d_ws, size_t ws_size,
                              hipStream_t stream) {
  const float* x      = (const float*)d_in[0];
  const float* qkv_w  = (const float*)d_in[1];
  const float* qkv_b  = (const float*)d_in[2];
  const float* proj_w = (const float*)d_in[3];
  const float* proj_b = (const float*)d_in[4];
  float* out = (float*)d_out;

  unsigned short* ws  = (unsigned short*)d_ws;
  unsigned short* kf  = ws + KOFF;
  unsigned short* vf  = ws + VOFF;
  unsigned int*   ctr = (unsigned int*)(ws + CTOFF);

  hipMemsetAsync(ctr, 0, 4, stream);
  k_fused<<<256, 512, 0, stream>>>(x, qkv_w, qkv_b, proj_w, proj_b,
                                   kf, vf, out, ctr);
}

// Round 12
// 110.019 us; speedup vs baseline: 1.7312x; 1.7312x over previous
//
#include <hip/hip_runtime.h>
#include <hip/hip_bf16.h>

// EfficientAttention: x(4,256,64,64) -> qkv(192ch) -> attn(N=4096,c=64) -> proj(256ch)
// R12: K-SPLIT attention. R0-R11 decomposition: period = 3.2us per 64KB staged
//   + 0.022us/chunk-unit => per-CU global-read service ~8.5 B/cyc is the wall;
//   every prior structure read 1MB/block (floor 51us = the "56us invariant").
//   Fix: grid 256 = (b, qt 16 q-groups x 256 rows, ks 4 k-quarters); each
//   block reads only 256KB (32 chunks K+V). O/den are pure sums -> fp32
//   partials to ws (no atomics; unique writer per (ks,b,row)), then k_comb
//   (256 blocks, 64 rows each) sums 4 partials, normalizes, and runs R6's
//   proj epilogue verbatim. Needs ~23.6MB ws -> guarded; fallback = R6 path
//   (kernel names in rocprof disambiguate which path ran).
// k_prep: qkv weights fp32->bf16 frag layout (QSC folded into Q rows/bias).
// k_qkv : R5 768-thr version (unchanged this round).
//   Qf/Kf: [b][chunk32][kk(4)][lane(64)][8]
//   Vf   : [b][chunk32][ct(2)ks(2)][lane(64)][j(8)] = producer reg order

#define N_TOK 4096
#define CDIM  64
#define DIM   256
#define NBAT  4

typedef __attribute__((ext_vector_type(8)))  short          short8;
typedef __attribute__((ext_vector_type(8)))  unsigned short ushort8_t;
typedef __attribute__((ext_vector_type(4)))  unsigned short ushort4_t;
typedef __attribute__((ext_vector_type(4)))  unsigned int   uint4_t;
typedef __attribute__((ext_vector_type(4)))  float          float4_t;
typedef __attribute__((ext_vector_type(16))) float          float16_t;

#if __has_builtin(__builtin_amdgcn_exp2f)
#define QSC  0.18033688011112042f   /* 0.125 * log2(e): p = exp2(s) */
#define PEXP(x) __builtin_amdgcn_exp2f(x)
#else
#define QSC  0.125f
#define PEXP(x) __expf(x)
#endif

__device__ __forceinline__ unsigned short f2bf(float f) {
  unsigned int u = __builtin_bit_cast(unsigned int, f);
  u += 0x7fffu + ((u >> 16) & 1u);            // RNE
  return (unsigned short)(u >> 16);
}

// packed f32x2 -> bf16x2 dword (v_cvt_pk_bf16_f32 on gfx950, RNE)
__device__ __forceinline__ unsigned int pkcv(float a, float b) {
  __hip_bfloat162 h = __float22bfloat162_rn(make_float2(a, b));
  unsigned int r; __builtin_memcpy(&r, &h, 4); return r;
}

__device__ __forceinline__ short8 ld8(const unsigned short* p) {
  return __builtin_bit_cast(short8, *(const ushort8_t*)p);
}

__device__ __forceinline__ short8 pack8f(float4_t a, float4_t b) {
  uint4_t u;
  u[0] = pkcv(a[0], a[1]); u[1] = pkcv(a[2], a[3]);
  u[2] = pkcv(b[0], b[1]); u[3] = pkcv(b[2], b[3]);
  return __builtin_bit_cast(short8, u);
}

__device__ __forceinline__ float16_t z16() {
  float16_t r;
#pragma unroll
  for (int i = 0; i < 16; ++i) r[i] = 0.0f;
  return r;
}

// async global->LDS DMA: 64 lanes x 16B; LDS dst = wave-uniform base (+lane*16 by HW)
typedef __attribute__((address_space(1))) const void* gvp;
typedef __attribute__((address_space(3))) void*       lvp;
__device__ __forceinline__ void dma16(const unsigned short* g, unsigned short* l) {
  __builtin_amdgcn_global_load_lds((gvp)g, (lvp)l, 16, 0, 0);
}

#define MFMA(a, b, c) __builtin_amdgcn_mfma_f32_32x32x16_bf16((a), (b), (c), 0, 0, 0)

// ws layout (u16 units)
#define QOFF  0                // Qf/Kf/Vf: 1048576 u16 each
#define KOFF  1048576
#define VOFF  2097152
#define WQOFF 3145728          // 192*256 bf16
#define BSOFF 3194880          // scaled qkv bias, fp32 (192)
#define OPOFF 3276800          // Opart fp32: 4ks*4b*4096R*64c = 8388608 u16
#define DNOFF (OPOFF + 8388608) // den fp32: 4ks*4b*4096 = 131072 u16
#define WS_NEED_U16 (DNOFF + 131072)

// ---------------------------------------------------------------------------
// k_prep: grid 24 x 256. qkv_w -> bf16 frag layout (Q rows scaled by QSC);
// bias -> fp32 with Q-scale fold.
// ---------------------------------------------------------------------------
__global__ void k_prep(const float* __restrict__ qw, const float* __restrict__ qb,
                       unsigned short* __restrict__ wqs, float* __restrict__ bs)
{
  const int g = blockIdx.x * 256 + threadIdx.x;   // 0..6143
  {
    const int lane = g & 63, grp = g >> 6;
    const int w6 = grp >> 4, kk = grp & 15;
    const int o = w6 * 32 + (lane & 31);
    const int c = kk * 16 + (lane >> 5) * 8;
    const float sc = (o < 64) ? QSC : 1.0f;
    const float* src = qw + o * 256 + c;
    ushort8_t u;
#pragma unroll
    for (int j = 0; j < 8; ++j) u[j] = f2bf(src[j] * sc);
    *(ushort8_t*)(wqs + g * 8) = u;
  }
  if (g < 48) {
    float4_t f = *(const float4_t*)(qb + g * 4);
    float4_t o;
#pragma unroll
    for (int j = 0; j < 4; ++j) o[j] = f[j] * ((g * 4 + j) < 64 ? QSC : 1.0f);
    *(float4_t*)(bs + g * 4) = o;
  }
}

// ---------------------------------------------------------------------------
// k_qkv: grid 256 x 768 thr (12 waves). Block: 64-token tile, all 192 o.
// Wave w: o-tile (w>>1), chunk (w&1). wf[16] hoisted pre-barrier.
// ---------------------------------------------------------------------------
#define RS 132   // Xl row stride in dwords

__global__ __launch_bounds__(768, 3) void k_qkv(
    const float* __restrict__ x, const unsigned short* __restrict__ wqs,
    const float* __restrict__ bs, unsigned short* __restrict__ Qf,
    unsigned short* __restrict__ Kf, unsigned short* __restrict__ Vf)
{
  __shared__ unsigned int Xl[64 * RS];
  const int id = blockIdx.x;
  const int b  = (id >> 1) & 3;
  const int nt = (id & 1) | ((id >> 3) << 1);   // 0..63 (64-token tile)
  const int t  = threadIdx.x;
  const int n0g = nt * 64;

  if (t < 512) {
    const int n0  = (t & 15) * 4;
    const int cpb = t >> 4;                      // 0..31
#pragma unroll
    for (int p = 0; p < 4; ++p) {
      const int cp = cpb + 32 * p, c = cp * 2;
      const float* xb = x + (((size_t)(b * DIM + c)) << 12) + n0g + n0;
      float4_t a = *(const float4_t*)xb;
      float4_t d = *(const float4_t*)(xb + 4096);
#pragma unroll
      for (int j = 0; j < 4; ++j)
        Xl[(n0 + j) * RS + cp] = pkcv(a[j], d[j]);
    }
  }

  const int w = t >> 6, lane = t & 63, l31 = lane & 31, lh = lane >> 5;
  const int ot = w >> 1, sub = w & 1;
  const int ch = nt * 2 + sub;                   // global 32-token chunk

  const unsigned short* wrow = wqs + ((ot * 16) << 9) + lane * 8;
  short8 wf[16];
#pragma unroll
  for (int kk = 0; kk < 16; ++kk) wf[kk] = ld8(wrow + (kk << 9));

  __syncthreads();

  const unsigned int* xr = &Xl[(sub * 32 + l31) * RS + lh * 4];

  float16_t a0 = z16();
  if (ot < 4) {
#pragma unroll
    for (int kk = 0; kk < 16; ++kk) {
      short8 xv = __builtin_bit_cast(short8, *(const uint4_t*)(xr + kk * 8));
      a0 = MFMA(wf[kk], xv, a0);                 // C[o rows][n cols]
    }
  } else {
#pragma unroll
    for (int kk = 0; kk < 16; ++kk) {
      short8 xv = __builtin_bit_cast(short8, *(const uint4_t*)(xr + kk * 8));
      a0 = MFMA(xv, wf[kk], a0);                 // C[token rows][c cols]
    }
  }

  if (ot < 4) {
    unsigned short* dst = (ot < 2) ? Qf : Kf;
    const int w2 = ot & 1;                       // c64-half of Q or K
#pragma unroll
    for (int p = 0; p < 4; ++p) {
      const int o = ot * 32 + p * 8 + lh * 4;    // global qkv channel
      float4_t bv = *(const float4_t*)(bs + o);
      ushort4_t pk4;
#pragma unroll
      for (int q = 0; q < 4; ++q) pk4[q] = f2bf(a0[p * 4 + q] + bv[q]);
      const int kkt = w2 * 2 + (p >> 1);
      *(ushort4_t*)(dst + ((((b * 128 + ch) * 4 + kkt) << 9)
                           + (l31 + 32 * (p & 1)) * 8 + lh * 4)) = pk4;
    }
  } else {
    const int ct = ot - 4;                       // c-group of V
    const float bvs = bs[128 + ct * 32 + l31];
#pragma unroll
    for (int ks = 0; ks < 2; ++ks) {
      ushort8_t pk8;
#pragma unroll
      for (int j = 0; j < 8; ++j) pk8[j] = f2bf(a0[ks * 8 + j] + bvs);
      *(ushort8_t*)(Vf + ((((b * 128 + ch) * 4 + ct * 2 + ks) << 9)
                          + lane * 8)) = pk8;
    }
  }
}

// ---------------------------------------------------------------------------
// k_attn_p: grid 256 x 512 thr (8 waves). Block = (b, qt 256-q group, ks
// k-quarter). Wave wv owns q-chunk qt*8+wv (32 rows), iterates the 32 chunks
// of its k-quarter as 4 tiles x 8 chunks (R8's staging/compute body: K+V
// DMA'd to LDS dbuf, one barrier per tile). O + den stay in-register, then
// written as fp32 PARTIALS to ws (unique writer per (ks,b,row) -> no atomics).
// Per-block global reads = 256KB (vs 1MB) = the byte-law lever.
// ---------------------------------------------------------------------------
__global__ __launch_bounds__(512, 1) void k_attn_p(
    const unsigned short* __restrict__ Qf, const unsigned short* __restrict__ Kf,
    const unsigned short* __restrict__ Vf, float* __restrict__ Opart,
    float* __restrict__ denp)
{
  __shared__ __align__(16) unsigned short KV[2][2][16384]; // [buf][K|V][8ch*2048]

  const int id = blockIdx.x;
  const int b  = (id >> 1) & 3;                      // batch pinned to XCD pair
  const int v  = (id & 1) | ((id >> 3) << 1);        // 0..63
  const int qt = v >> 2;                             // 0..15 (256-q group)
  const int ks = v & 3;                              // k-quarter (32 chunks)
  const int t  = threadIdx.x;
  const int wv = t >> 6, lane = t & 63, l31 = lane & 31, lh = lane >> 5;

  // Q frags of the wave's OWN 32-q chunk (QSC pre-folded)
  const int cq = qt * 8 + wv;
  short8 qf[4];
#pragma unroll
  for (int kk = 0; kk < 4; ++kk)
    qf[kk] = ld8(Qf + (((b * 128 + cq) * 4 + kk) << 9) + lane * 8);

  // staging: wave stages chunk wv (K + V) of each 8-chunk tile of its quarter
  const unsigned short* sgK = Kf + (((size_t)(b * 128 + ks * 32 + wv)) << 11) + lane * 8;
  const unsigned short* sgV = Vf + (((size_t)(b * 128 + ks * 32 + wv)) << 11) + lane * 8;

  // stage tile 0 into buf 0
#pragma unroll
  for (int kk = 0; kk < 4; ++kk)
    dma16(sgK + (kk << 9), &KV[0][0][(wv << 11) + (kk << 9)]);
#pragma unroll
  for (int kk = 0; kk < 4; ++kk)
    dma16(sgV + (kk << 9), &KV[0][1][(wv << 11) + (kk << 9)]);

  float16_t oc0 = z16(), oc1 = z16();   // O partial: col = ct*32+l31... (S^T layout)
  float den = 0.0f;

  __syncthreads();   // tile 0 resident

  for (int t4 = 0; t4 < 4; ++t4) {
    const int cur = t4 & 1;

    if (t4 < 3) {
      const size_t go = ((size_t)(t4 + 1)) << 14;
#pragma unroll
      for (int kk = 0; kk < 4; ++kk)
        dma16(sgK + go + (kk << 9), &KV[cur ^ 1][0][(wv << 11) + (kk << 9)]);
#pragma unroll
      for (int kk = 0; kk < 4; ++kk)
        dma16(sgV + go + (kk << 9), &KV[cur ^ 1][1][(wv << 11) + (kk << 9)]);
    }

#pragma unroll
    for (int cc = 0; cc < 8; ++cc) {
      const unsigned short* kl = &KV[cur][0][cc << 11];
      const unsigned short* vl = &KV[cur][1][cc << 11];

      short8 kf0 = ld8(kl + lane * 8);
      short8 kf1 = ld8(kl + 512 + lane * 8);
      short8 kf2 = ld8(kl + 1024 + lane * 8);
      short8 kf3 = ld8(kl + 1536 + lane * 8);

      // S^T tile: lane col n = l31 (q-row), row m = (e&3)+8*(e>>2)+4*lh
      float16_t s = z16();
      s = MFMA(kf0, qf[0], s);
      s = MFMA(kf1, qf[1], s);
      s = MFMA(kf2, qf[2], s);
      s = MFMA(kf3, qf[3], s);

      float p[16];
#pragma unroll
      for (int e = 0; e < 16; ++e) p[e] = PEXP(s[e]);
      {
        float d0 = (p[0] + p[1]) + (p[2] + p[3]);
        float d1 = (p[4] + p[5]) + (p[6] + p[7]);
        float d2 = (p[8] + p[9]) + (p[10] + p[11]);
        float d3 = (p[12] + p[13]) + (p[14] + p[15]);
        den += (d0 + d1) + (d2 + d3);
      }

      uint4_t w0, w1;
#pragma unroll
      for (int j = 0; j < 4; ++j) {
        w0[j] = pkcv(p[2 * j], p[2 * j + 1]);
        w1[j] = pkcv(p[8 + 2 * j], p[9 + 2 * j]);
      }
      short8 pf0 = __builtin_bit_cast(short8, w0);   // m 0..15 of chunk
      short8 pf1 = __builtin_bit_cast(short8, w1);   // m 16..31

      short8 vf0 = ld8(vl + lane * 8);               // ct0 ks0
      short8 vf1 = ld8(vl + 512 + lane * 8);         // ct0 ks1
      short8 vf2 = ld8(vl + 1024 + lane * 8);        // ct1 ks0
      short8 vf3 = ld8(vl + 1536 + lane * 8);        // ct1 ks1

      oc0 = MFMA(pf0, vf0, oc0);
      oc0 = MFMA(pf1, vf1, oc0);
      oc1 = MFMA(pf0, vf2, oc1);
      oc1 = MFMA(pf1, vf3, oc1);
    }

    __syncthreads();   // drains next-tile DMA + frees cur buffer
  }

  // full denominator per q-row over this k-quarter (lh halves combined)
  den += __shfl_xor(den, 32);

  // write fp32 partials (unique writer; coalesced 128B per (e,ct) half-wave)
  float* op = Opart + (((size_t)(ks * 4 + b) * 4096) + qt * 256 + wv * 32) * 64;
#pragma unroll
  for (int e = 0; e < 16; ++e) {
    const int r = (e & 3) + 8 * (e >> 2) + 4 * lh;   // q-row within chunk
    op[r * 64 + l31]      = oc0[e];
    op[r * 64 + 32 + l31] = oc1[e];
  }
  if (lane < 32)
    denp[((size_t)(ks * 4 + b) * 4096) + qt * 256 + wv * 32 + l31] = den;
}

// ---------------------------------------------------------------------------
// k_comb: grid 256 x 512 thr. Block = (b, nt 64-row group). Sum 4 k-quarter
// partials + den, normalize -> Ol bf16, then R6's proj epilogue verbatim.
// ---------------------------------------------------------------------------
#define OLS  72    // Ol row stride (bf16)

__global__ __launch_bounds__(512, 2) void k_comb(
    const float* __restrict__ Opart, const float* __restrict__ denp,
    const float* __restrict__ pw, const float* __restrict__ pb,
    float* __restrict__ out)
{
  __shared__ __align__(16) unsigned short Ol[64 * OLS];

  const int id = blockIdx.x;
  const int b  = (id >> 1) & 3;
  const int nt = (id & 1) | ((id >> 3) << 1);        // 0..63 (64-row group)
  const int t  = threadIdx.x;
  const int wv = t >> 6, lane = t & 63, l31 = lane & 31, lh = lane >> 5;

  // normalize: 8 thr/row over 64 rows
  {
    const int nloc = t >> 3, c8 = (t & 7) * 8;
    const size_t R = (size_t)nt * 64 + nloc;         // row within batch
    float4_t s0 = {0.f, 0.f, 0.f, 0.f}, s1 = {0.f, 0.f, 0.f, 0.f};
    float d = 0.0f;
#pragma unroll
    for (int ks = 0; ks < 4; ++ks) {
      const float* op = Opart + (((size_t)(ks * 4 + b) * 4096) + R) * 64 + c8;
      float4_t a0 = *(const float4_t*)op;
      float4_t a1 = *(const float4_t*)(op + 4);
#pragma unroll
      for (int j = 0; j < 4; ++j) { s0[j] += a0[j]; s1[j] += a1[j]; }
      d += denp[((size_t)(ks * 4 + b) * 4096) + R];
    }
    const float r = 1.0f / d;
    uint4_t o4;
    o4[0] = pkcv(s0[0] * r, s0[1] * r);
    o4[1] = pkcv(s0[2] * r, s0[3] * r);
    o4[2] = pkcv(s1[0] * r, s1[1] * r);
    o4[3] = pkcv(s1[2] * r, s1[3] * r);
    *(uint4_t*)&Ol[nloc * OLS + c8] = o4;
  }
  __syncthreads();

  // fused proj: wave wv -> o-tile wv (32 o), both n-subtiles; raw fp32 W
  float16_t f0 = z16(), f1 = z16();
  const float* pwrow = pw + (wv * 32 + l31) * 64 + lh * 8;
#pragma unroll
  for (int kk = 0; kk < 4; ++kk) {
    float4_t wa = *(const float4_t*)(pwrow + kk * 16);
    float4_t wb = *(const float4_t*)(pwrow + kk * 16 + 4);
    short8 af = pack8f(wa, wb);
    short8 b0 = ld8(&Ol[l31 * OLS + kk * 16 + lh * 8]);
    short8 b1 = ld8(&Ol[(32 + l31) * OLS + kk * 16 + lh * 8]);
    f0 = MFMA(af, b0, f0);
    f1 = MFMA(af, b1, f1);
  }
  const int n0 = nt * 64;
#pragma unroll
  for (int e = 0; e < 16; ++e) {
    const int o = wv * 32 + (e & 3) + 8 * (e >> 2) + 4 * lh;
    const float bv = pb[o];
    out[((b * 256 + o) << 12) + n0 + l31]      = f0[e] + bv;
    out[((b * 256 + o) << 12) + n0 + 32 + l31] = f1[e] + bv;
  }
}

// ---------------------------------------------------------------------------
// k_attn: R6 fallback (ws too small for partials). 256 x 512 thr, 56us.
// ---------------------------------------------------------------------------
#define OS   68    // Oacc row stride (fp32)
#define NACC (64 * OS + 64)

__global__ __launch_bounds__(512, 1) void k_attn(
    const unsigned short* __restrict__ Qf, const unsigned short* __restrict__ Kf,
    const unsigned short* __restrict__ Vf, const float* __restrict__ pw,
    const float* __restrict__ pb, float* __restrict__ out)
{
  __shared__ __align__(16) unsigned short Kl[2][32768];    // [buf][16ch*2048]
  __shared__ float Oacc[NACC];
  __shared__ __align__(16) unsigned short Ol[64 * OLS];

  const int id = blockIdx.x;
  const int b  = (id >> 1) & 3;
  const int nt = (id & 1) | ((id >> 3) << 1);
  const int t  = threadIdx.x;
  const int wv = t >> 6, lane = t & 63, l31 = lane & 31, lh = lane >> 5;
  const int mq = wv >> 1, nsub = wv & 1;

  for (int i = t; i < NACC; i += 512) Oacc[i] = 0.0f;

  const int wq2 = wv * 2;
  const unsigned short* sg = Kf + (((size_t)(b * 128 + wq2)) << 11) + lane * 8;

  short8 qf[4];
#pragma unroll
  for (int kk = 0; kk < 4; ++kk)
    qf[kk] = ld8(Qf + (((b * 128 + nt * 2 + nsub) * 4 + kk) << 9) + lane * 8);

  const unsigned short* vbase = Vf + (((size_t)(b * 128)) << 11) + lane * 8;

#pragma unroll
  for (int c2 = 0; c2 < 2; ++c2)
#pragma unroll
    for (int kk = 0; kk < 4; ++kk)
      dma16(sg + (c2 << 11) + (kk << 9),
            &Kl[0][((wq2 + c2) << 11) + (kk << 9)]);

  float16_t oc0 = z16(), oc1 = z16();
  float den = 0.0f;

  __syncthreads();

  for (int t8 = 0; t8 < 8; ++t8) {
    const int cur = t8 & 1;

    if (t8 < 7) {
      const unsigned short* g = sg + (((size_t)(t8 + 1)) << 15);
#pragma unroll
      for (int c2 = 0; c2 < 2; ++c2)
#pragma unroll
        for (int kk = 0; kk < 4; ++kk)
          dma16(g + (c2 << 11) + (kk << 9),
                &Kl[cur ^ 1][((wq2 + c2) << 11) + (kk << 9)]);
    }

#pragma unroll
    for (int cc = 0; cc < 4; ++cc) {
      const int ch = mq * 4 + cc;
      const unsigned short* kl = &Kl[cur][ch << 11];

      short8 kf0 = ld8(kl + lane * 8);
      short8 kf1 = ld8(kl + 512 + lane * 8);
      short8 kf2 = ld8(kl + 1024 + lane * 8);
      short8 kf3 = ld8(kl + 1536 + lane * 8);

      float16_t s = z16();
      s = MFMA(kf0, qf[0], s);
      s = MFMA(kf1, qf[1], s);
      s = MFMA(kf2, qf[2], s);
      s = MFMA(kf3, qf[3], s);

      float p[16];
#pragma unroll
      for (int e = 0; e < 16; ++e) p[e] = PEXP(s[e]);
      {
        float d0 = (p[0] + p[1]) + (p[2] + p[3]);
        float d1 = (p[4] + p[5]) + (p[6] + p[7]);
        float d2 = (p[8] + p[9]) + (p[10] + p[11]);
        float d3 = (p[12] + p[13]) + (p[14] + p[15]);
        den += (d0 + d1) + (d2 + d3);
      }

      uint4_t w0, w1;
#pragma unroll
      for (int j = 0; j < 4; ++j) {
        w0[j] = pkcv(p[2 * j], p[2 * j + 1]);
        w1[j] = pkcv(p[8 + 2 * j], p[9 + 2 * j]);
      }
      short8 pf0 = __builtin_bit_cast(short8, w0);
      short8 pf1 = __builtin_bit_cast(short8, w1);

      const unsigned short* vl = vbase + (((size_t)(t8 * 16 + ch)) << 11);
      short8 vf0 = ld8(vl);
      short8 vf1 = ld8(vl + 512);
      short8 vf2 = ld8(vl + 1024);
      short8 vf3 = ld8(vl + 1536);

      oc0 = MFMA(pf0, vf0, oc0);
      oc0 = MFMA(pf1, vf1, oc0);
      oc1 = MFMA(pf0, vf2, oc1);
      oc1 = MFMA(pf1, vf3, oc1);
    }

    __syncthreads();
  }

  den += __shfl_xor(den, 32);

#pragma unroll
  for (int ct = 0; ct < 2; ++ct) {
    const float16_t& oa = ct ? oc1 : oc0;
    const int cc = ct * 32 + l31;
#pragma unroll
    for (int e = 0; e < 16; ++e) {
      const int nr = nsub * 32 + (e & 3) + 8 * (e >> 2) + 4 * lh;
      atomicAdd(&Oacc[nr * OS + cc], oa[e]);
    }
  }
  if (lane < 32) atomicAdd(&Oacc[64 * OS + nsub * 32 + l31], den);
  __syncthreads();

  {
    const int nloc = t >> 3, c8 = (t & 7) * 8;
    float4_t s0 = *(float4_t*)&Oacc[nloc * OS + c8];
    float4_t s1 = *(float4_t*)&Oacc[nloc * OS + c8 + 4];
    const float r = 1.0f / Oacc[64 * OS + nloc];
    uint4_t o4;
    o4[0] = pkcv(s0[0] * r, s0[1] * r);
    o4[1] = pkcv(s0[2] * r, s0[3] * r);
    o4[2] = pkcv(s1[0] * r, s1[1] * r);
    o4[3] = pkcv(s1[2] * r, s1[3] * r);
    *(uint4_t*)&Ol[nloc * OLS + c8] = o4;
  }
  __syncthreads();

  float16_t f0 = z16(), f1 = z16();
  const float* pwrow = pw + (wv * 32 + l31) * 64 + lh * 8;
#pragma unroll
  for (int kk = 0; kk < 4; ++kk) {
    float4_t wa = *(const float4_t*)(pwrow + kk * 16);
    float4_t wb = *(const float4_t*)(pwrow + kk * 16 + 4);
    short8 af = pack8f(wa, wb);
    short8 b0 = ld8(&Ol[l31 * OLS + kk * 16 + lh * 8]);
    short8 b1 = ld8(&Ol[(32 + l31) * OLS + kk * 16 + lh * 8]);
    f0 = MFMA(af, b0, f0);
    f1 = MFMA(af, b1, f1);
  }
  const int n0 = nt * 64;
#pragma unroll
  for (int e = 0; e < 16; ++e) {
    const int o = wv * 32 + (e & 3) + 8 * (e >> 2) + 4 * lh;
    const float bv = pb[o];
    out[((b * 256 + o) << 12) + n0 + l31]      = f0[e] + bv;
    out[((b * 256 + o) << 12) + n0 + 32 + l31] = f1[e] + bv;
  }
}

extern "C" void kernel_launch(void* const* d_in, const int* in_sizes, int n_in,
                              void* d_out, int out_size, void* d_ws, size_t ws_size,
                              hipStream_t stream) {
  const float* x      = (const float*)d_in[0];
  const float* qkv_w  = (const float*)d_in[1];
  const float* qkv_b  = (const float*)d_in[2];
  const float* proj_w = (const float*)d_in[3];
  const float* proj_b = (const float*)d_in[4];
  float* out = (float*)d_out;

  unsigned short* ws  = (unsigned short*)d_ws;
  unsigned short* qf  = ws + QOFF;
  unsigned short* kf  = ws + KOFF;
  unsigned short* vf  = ws + VOFF;
  unsigned short* wqs = ws + WQOFF;
  float*          bs  = (float*)(ws + BSOFF);
  float*          op  = (float*)(ws + OPOFF);
  float*          dn  = (float*)(ws + DNOFF);

  k_prep<<<24, 256, 0, stream>>>(qkv_w, qkv_b, wqs, bs);
  k_qkv<<<256, 768, 0, stream>>>(x, wqs, bs, qf, kf, vf);

  if (ws_size >= (size_t)WS_NEED_U16 * 2) {
    k_attn_p<<<256, 512, 0, stream>>>(qf, kf, vf, op, dn);
    k_comb<<<256, 512, 0, stream>>>(op, dn, proj_w, proj_b, out);
  } else {
    k_attn<<<256, 512, 0, stream>>>(qf, kf, vf, proj_w, proj_b, out);
  }
}